// Round 6
// baseline (9002.899 us; speedup 1.0000x reference)
//
#include <hip/hip_runtime.h>

// ---------------- problem constants ----------------
#define NN      16384      // total nodes
#define TSTEPS  32
#define SG      256        // graphs
#define NE      262144
#define NPANEL  24         // 22 panels for xl@Wih (21x384 + 128) + 2 for lh@Whh (384+128)
#define GSTRIDE 524288u    // 256*2048 floats per panel partial

// ---------------- workspace layout (float offsets) ----------------
#define OFF_ENC_MEM   0u
#define OFF_ENC_SPK   2097152u
#define OFF_C1_MEM    4194304u
#define OFF_C1_SPK    6291456u     // == xl [256][8192]
#define OFF_LH        8388608u
#define OFF_LC        8519680u
#define OFF_H1_MEM    8650752u
#define OFF_H1_SPK    8716288u
#define OFF_H2_MEM    8781824u
#define OFF_H2_SPK    8782848u
#define OFF_H2_SUM    8783872u
#define ZERO_FLOATS   8784896u     // everything below here zeroed each launch
#define OFF_BASES     8784896u
#define OFF_COMB      9833472u
#define OFF_GATES     10357760u    // 256 x 2048
#define OFF_PART      10882048u    // 24 x 256 x 2048 panel partials
#define OFF_DINV      23464960u
#define OFF_COLW      23481344u
#define FLOAT_END     23743488u
// int region (offsets from ibase)
#define IOFF_DEG      0
#define IOFF_FILL     16384
#define IOFF_ROWPTR   32768
#define IOFF_EID      49153
#define IOFF_COL      311297
#define INT_COUNT     573441

// ---------------- graph preprocessing ----------------
__global__ void k_deg(const int* __restrict__ ei, int* __restrict__ deg) {
  int e = blockIdx.x * 256 + threadIdx.x;
  if (e < NE) atomicAdd(&deg[ei[NE + e]], 1);
}

__global__ void k_dinv(const int* __restrict__ deg, float* __restrict__ dinv) {
  int n = blockIdx.x * 256 + threadIdx.x;
  if (n < NN) dinv[n] = __fdiv_rn(1.0f, __fsqrt_rn((float)(deg[n] + 1)));  // +1 self-loop
}

__global__ void k_scan(const int* __restrict__ deg, int* __restrict__ rowp) {
  __shared__ int sdata[1024];
  int tid = threadIdx.x;
  int base = tid * 16;
  int loc[16];
  int sum = 0;
  #pragma unroll
  for (int i = 0; i < 16; ++i) { loc[i] = sum; sum += deg[base + i]; }
  sdata[tid] = sum;
  __syncthreads();
  for (int off = 1; off < 1024; off <<= 1) {
    int v = 0;
    if (tid >= off) v = sdata[tid - off];
    __syncthreads();
    sdata[tid] += v;
    __syncthreads();
  }
  int excl = (tid == 0) ? 0 : sdata[tid - 1];
  #pragma unroll
  for (int i = 0; i < 16; ++i) rowp[base + i] = excl + loc[i];
  if (tid == 1023) rowp[NN] = sdata[1023];
}

__global__ void k_scatter(const int* __restrict__ ei, const int* __restrict__ rowp,
                          int* __restrict__ fill, int* __restrict__ eid) {
  int e = blockIdx.x * 256 + threadIdx.x;
  if (e >= NE) return;
  int d = ei[NE + e];
  int pos = rowp[d] + atomicAdd(&fill[d], 1);
  eid[pos] = e;
}

// sort each adjacency list by EDGE ID (unique keys) -> summation order == scatter-add order
__global__ void k_sortadj(const int* __restrict__ rowp, int* __restrict__ eid,
                          const int* __restrict__ ei, const float* __restrict__ dinv,
                          int* __restrict__ col, float* __restrict__ colw) {
  int d = blockIdx.x * 256 + threadIdx.x;
  if (d >= NN) return;
  int r0 = rowp[d], r1 = rowp[d + 1];
  for (int i = r0 + 1; i < r1; ++i) {
    int key = eid[i];
    int j = i - 1;
    while (j >= r0 && eid[j] > key) { eid[j + 1] = eid[j]; --j; }
    eid[j + 1] = key;
  }
  for (int i = r0; i < r1; ++i) {
    int s = ei[eid[i]];
    col[i] = s;
    colw[i] = dinv[s];
  }
}

// ---------------- per-timestep kernels ----------------
// fused enc LIF + bases/comb matmuls (64 nodes/block).
__global__ __launch_bounds__(256) void k_encbases(
    const float* __restrict__ x, const float* __restrict__ encW, const float* __restrict__ encB,
    float* __restrict__ enc_mem, float* __restrict__ enc_spk,
    const float* __restrict__ basesW, const float* __restrict__ basesB,
    const float* __restrict__ combW, const float* __restrict__ combB,
    float* __restrict__ bases, float* __restrict__ comb, int t) {
  __shared__ float xs[64][8];
  __shared__ float sp[64 * 129];   // [node][j]
  __shared__ float ob[64 * 65];    // bases out [node][ch]
  __shared__ float oc[64 * 33];    // comb out [node][ch]
  const int tid = threadIdx.x;
  const int nb = blockIdx.x * 64;
  #pragma unroll
  for (int r = 0; r < 2; ++r) {
    int idx = r * 256 + tid;       // 0..511
    int n = idx >> 3, c = idx & 7;
    xs[n][c] = x[(size_t)(nb + n) * 256 + (size_t)c * 32 + t];
  }
  __syncthreads();
  #pragma unroll 4
  for (int k = 0; k < 32; ++k) {
    int idx = k * 256 + tid;
    int n = idx >> 7, j = idx & 127;
    float dot = 0.f;
    #pragma unroll
    for (int c = 0; c < 8; ++c) dot = __fmaf_rn(xs[n][c], encW[c * 128 + j], dot);
    size_t gi = (size_t)nb * 128 + idx;
    float m = enc_mem[gi], s = enc_spk[gi];
    float nm = __fadd_rn(__fadd_rn(__fmul_rn(__fmul_rn(m, 0.2f), __fsub_rn(1.f, s)), dot), encB[j]);
    enc_mem[gi] = nm;
    float spike = nm > 0.5f ? 1.f : 0.f;
    enc_spk[gi] = spike;
    sp[n * 129 + j] = spike;
  }
  __syncthreads();
  const int lane = tid & 63;
  const int w = tid >> 6;
  const float* spn = sp + lane * 129;
  if (w < 2) {
    const int ch0 = w * 32;
    const float* Wp = basesW + ch0;
    float acc[32];
    #pragma unroll
    for (int c = 0; c < 32; ++c) acc[c] = 0.f;
    for (int j = 0; j < 128; ++j) {
      const float s = spn[j];
      const float* wr = Wp + j * 64;
      #pragma unroll
      for (int c = 0; c < 32; ++c) acc[c] = __fmaf_rn(s, wr[c], acc[c]);
    }
    #pragma unroll
    for (int c = 0; c < 32; ++c) ob[lane * 65 + ch0 + c] = acc[c];
  } else {
    const int ch0 = (w - 2) * 16;
    const float* Wp = combW + ch0;
    float acc[16];
    #pragma unroll
    for (int c = 0; c < 16; ++c) acc[c] = 0.f;
    for (int j = 0; j < 128; ++j) {
      const float s = spn[j];
      const float* wr = Wp + j * 32;
      #pragma unroll
      for (int c = 0; c < 16; ++c) acc[c] = __fmaf_rn(s, wr[c], acc[c]);
    }
    #pragma unroll
    for (int c = 0; c < 16; ++c) oc[lane * 33 + ch0 + c] = acc[c];
  }
  __syncthreads();
  #pragma unroll
  for (int r = 0; r < 16; ++r) {
    int idx = r * 256 + tid;
    int n = idx >> 6, ch = idx & 63;
    bases[(size_t)(nb + n) * 64 + ch] = __fadd_rn(ob[n * 65 + ch], basesB[ch]);
  }
  #pragma unroll
  for (int r = 0; r < 8; ++r) {
    int idx = r * 256 + tid;
    int n = idx >> 5, ch = idx & 31;
    comb[(size_t)(nb + n) * 32 + ch] = __fadd_rn(oc[n * 33 + ch], combB[ch]);
  }
}

// fused: symnorm aggregation (edge-order scatter-add) -> einsum -> conv LIF -> c1 spike
__global__ __launch_bounds__(256) void k_aggconv(
    const float* __restrict__ bases, const float* __restrict__ comb,
    const float* __restrict__ dinv, const int* __restrict__ rowp,
    const int* __restrict__ col, const float* __restrict__ colw,
    const float* __restrict__ convB,
    float* __restrict__ c1_mem, float* __restrict__ c1_spk) {
  __shared__ float aggl[4][64];
  __shared__ float combl[4][32];
  int w = threadIdx.x >> 6;
  int m = threadIdx.x & 63;
  int d = blockIdx.x * 4 + w;
  float dd = dinv[d];
  int r0 = rowp[d], r1 = rowp[d + 1];
  float acc = 0.f;
  for (int r = r0; r < r1; ++r) {
    int s = col[r];
    float ew  = __fmul_rn(colw[r], dd);
    float upd = __fmul_rn(ew, bases[(size_t)s * 64 + m]);
    acc = __fadd_rn(acc, upd);
  }
  {
    float ew  = __fmul_rn(dd, dd);
    float upd = __fmul_rn(ew, bases[(size_t)d * 64 + m]);
    acc = __fadd_rn(acc, upd);
  }
  aggl[w][m] = acc;
  if (m < 32) combl[w][m] = comb[(size_t)d * 32 + m];
  __syncthreads();
  #pragma unroll
  for (int half = 0; half < 2; ++half) {
    int j = m + half * 64;
    int h = j >> 4, f = j & 15;
    float cv = 0.f;
    #pragma unroll
    for (int b = 0; b < 4; ++b)
      cv = __fadd_rn(cv, __fmul_rn(combl[w][h * 4 + b], aggl[w][b * 16 + f]));
    cv = __fadd_rn(cv, convB[j]);
    int idx = d * 128 + j;
    float cm = c1_mem[idx], cs = c1_spk[idx];
    float nm = __fadd_rn(__fmul_rn(__fmul_rn(cm, 0.2f), __fsub_rn(1.f, cs)), cv);
    c1_mem[idx] = nm;
    c1_spk[idx] = nm > 0.5f ? 1.f : 0.f;
  }
}

// one BLAS panel of the gates GEMM: part[z] = A[:, panel_z] @ B[panel_z, :]
// BM=128, BN=256, BK=16, 256 threads, 8x16 per-thread tile:
// 6 ds_read_b128 per 128 fma -> LDS:VALU = 1.125 per CU (VALU-bound), vs 1.5 at 8x8.
// Next tile's A/B prefetched into registers during compute (global latency hidden).
// acc chain stays ascending-k fma-from-0 per (m,u) -> bit-exact.
__global__ __launch_bounds__(256, 2) void k_gpanel(
    const float* __restrict__ xl, const float* __restrict__ lh,
    const float* __restrict__ Wih, const float* __restrict__ Whh,
    float* __restrict__ part) {
  __shared__ __align__(16) float Ast[16][132];   // [k][m] transposed, 8.4 KB
  __shared__ __align__(16) float Bs[16][260];    // [k][n], 16.6 KB
  const int tid = threadIdx.x;
  const int tx = tid & 15, ty = tid >> 4;
  const int n0 = blockIdx.x * 256;
  const int m0 = blockIdx.y * 128;
  const int z  = blockIdx.z;

  const float* Asrc; const float* Bsrc; int lda, k0, klen;
  if (z < 22) { Asrc = xl; Bsrc = Wih; lda = 8192; k0 = z * 384; klen = (z == 21) ? 128 : 384; }
  else        { Asrc = lh; Bsrc = Whh; lda = 512;  k0 = (z == 22) ? 0 : 384; klen = (z == 22) ? 384 : 128; }

  float acc[8][16];
  #pragma unroll
  for (int i = 0; i < 8; ++i)
    #pragma unroll
    for (int j = 0; j < 16; ++j) acc[i][j] = 0.f;

  const int arow = tid >> 1;            // 0..127
  const int acol = (tid & 1) * 8;       // 0 or 8
  const int brow = tid >> 6;            // 0..3 (+4,+8,+12)
  const int bcol = (tid & 63) * 4;      // 0..252

  float4 aR0, aR1, bR0, bR1, bR2, bR3;
  const int nkt = klen >> 4;

  {  // prologue: tile 0 -> regs
    const float* asp = Asrc + (size_t)(m0 + arow) * lda + k0 + acol;
    aR0 = ((const float4*)asp)[0];
    aR1 = ((const float4*)asp)[1];
    const float* bsp = Bsrc + (size_t)k0 * 2048 + n0 + bcol;
    bR0 = *(const float4*)(bsp + (size_t)(brow     ) * 2048);
    bR1 = *(const float4*)(bsp + (size_t)(brow +  4) * 2048);
    bR2 = *(const float4*)(bsp + (size_t)(brow +  8) * 2048);
    bR3 = *(const float4*)(bsp + (size_t)(brow + 12) * 2048);
  }

  for (int kt = 0; kt < nkt; ++kt) {
    __syncthreads();
    // staged regs -> LDS
    Ast[acol + 0][arow] = aR0.x; Ast[acol + 1][arow] = aR0.y;
    Ast[acol + 2][arow] = aR0.z; Ast[acol + 3][arow] = aR0.w;
    Ast[acol + 4][arow] = aR1.x; Ast[acol + 5][arow] = aR1.y;
    Ast[acol + 6][arow] = aR1.z; Ast[acol + 7][arow] = aR1.w;
    *(float4*)&Bs[brow     ][bcol] = bR0;
    *(float4*)&Bs[brow +  4][bcol] = bR1;
    *(float4*)&Bs[brow +  8][bcol] = bR2;
    *(float4*)&Bs[brow + 12][bcol] = bR3;
    __syncthreads();
    if (kt + 1 < nkt) {   // prefetch next tile into regs (overlaps compute)
      const int kb = k0 + ((kt + 1) << 4);
      const float* asp = Asrc + (size_t)(m0 + arow) * lda + kb + acol;
      aR0 = ((const float4*)asp)[0];
      aR1 = ((const float4*)asp)[1];
      const float* bsp = Bsrc + (size_t)kb * 2048 + n0 + bcol;
      bR0 = *(const float4*)(bsp + (size_t)(brow     ) * 2048);
      bR1 = *(const float4*)(bsp + (size_t)(brow +  4) * 2048);
      bR2 = *(const float4*)(bsp + (size_t)(brow +  8) * 2048);
      bR3 = *(const float4*)(bsp + (size_t)(brow + 12) * 2048);
    }
    #pragma unroll
    for (int kk = 0; kk < 16; ++kk) {
      const float4 a0 = *(const float4*)&Ast[kk][ty * 4];
      const float4 a1 = *(const float4*)&Ast[kk][64 + ty * 4];
      const float4 b0 = *(const float4*)&Bs[kk][tx * 4];
      const float4 b1 = *(const float4*)&Bs[kk][64 + tx * 4];
      const float4 b2 = *(const float4*)&Bs[kk][128 + tx * 4];
      const float4 b3 = *(const float4*)&Bs[kk][192 + tx * 4];
      const float av[8]  = {a0.x, a0.y, a0.z, a0.w, a1.x, a1.y, a1.z, a1.w};
      const float bv[16] = {b0.x, b0.y, b0.z, b0.w, b1.x, b1.y, b1.z, b1.w,
                            b2.x, b2.y, b2.z, b2.w, b3.x, b3.y, b3.z, b3.w};
      #pragma unroll
      for (int i = 0; i < 8; ++i)
        #pragma unroll
        for (int j = 0; j < 16; ++j)
          acc[i][j] = __fmaf_rn(av[i], bv[j], acc[i][j]);
    }
  }
  float* dstz = part + (size_t)z * GSTRIDE + (size_t)m0 * 2048 + n0;
  #pragma unroll
  for (int i = 0; i < 8; ++i) {
    const int mr = ((i >> 2) << 6) + ty * 4 + (i & 3);
    float* row = dstz + (size_t)mr * 2048;
    #pragma unroll
    for (int f = 0; f < 4; ++f)
      *(float4*)(row + f * 64 + tx * 4) =
          make_float4(acc[i][f*4+0], acc[i][f*4+1], acc[i][f*4+2], acc[i][f*4+3]);
  }
}

// combine panel partials strictly left-to-right (matches round-2 "tih += accP" chain)
__global__ __launch_bounds__(256) void k_combine(
    const float* __restrict__ part, const float* __restrict__ bih,
    const float* __restrict__ bhh, float* __restrict__ gates) {
  const int idx = blockIdx.x * 256 + threadIdx.x;    // m*2048 + u
  const float* p = part + idx;
  float tih = p[0];
  #pragma unroll
  for (int zz = 1; zz < 22; ++zz) tih = __fadd_rn(tih, p[(size_t)zz * GSTRIDE]);
  const float thh = __fadd_rn(p[22u * GSTRIDE], p[23u * GSTRIDE]);
  const int u = idx & 2047;
  gates[idx] = __fadd_rn(__fadd_rn(__fadd_rn(tih, bih[u]), thh), bhh[u]);
}

// fused: gate spikes -> LSTM cell -> fc1 LIF (384+128 panels) -> fc2 LIF -> h2 accum
__global__ __launch_bounds__(256) void k_cell(
    const float* __restrict__ gates,
    float* __restrict__ lc, float* __restrict__ lh,
    const float* __restrict__ fc1W, const float* __restrict__ fc1b,
    const float* __restrict__ fc2W, const float* __restrict__ fc2b,
    float* __restrict__ h1_mem, float* __restrict__ h1_spk,
    float* __restrict__ h2_mem, float* __restrict__ h2_spk, float* __restrict__ h2_sum) {
  __shared__ float lhl[512];
  __shared__ float sp1l[256];
  const int s = blockIdx.x;
  const int p = threadIdx.x;
  #pragma unroll
  for (int half = 0; half < 2; ++half) {
    const int h = p + half * 256;
    const float giv = gates[(size_t)s * 2048 + h];
    const float gfv = gates[(size_t)s * 2048 + 512 + h];
    const float ggv = gates[(size_t)s * 2048 + 1024 + h];
    const float gov = gates[(size_t)s * 2048 + 1536 + h];
    const float iv = giv > 0.f ? 1.f : 0.f;
    const float fv = gfv > 0.f ? 1.f : 0.f;
    const float gv = ggv > 0.f ? 1.f : 0.f;
    const float ov = gov > 0.f ? 1.f : 0.f;
    const int li = s * 512 + h;
    const float lcv = __fadd_rn(__fmul_rn(fv, lc[li]), __fmul_rn(iv, gv));
    lc[li] = lcv;
    const float lhv = __fmul_rn(lcv, ov);
    lh[li] = lhv;
    lhl[h] = lhv;
  }
  __syncthreads();
  float a0 = 0.f, a1 = 0.f;
  #pragma unroll 8
  for (int q = 0; q < 384; ++q) a0 = __fmaf_rn(lhl[q], fc1W[q * 256 + p], a0);
  #pragma unroll 8
  for (int q = 384; q < 512; ++q) a1 = __fmaf_rn(lhl[q], fc1W[q * 256 + p], a1);
  const float dot1 = __fadd_rn(a0, a1);
  const int i1 = s * 256 + p;
  const float m1 = h1_mem[i1], s1o = h1_spk[i1];
  const float nm1 = __fadd_rn(__fadd_rn(__fmul_rn(__fmul_rn(m1, 0.2f), __fsub_rn(1.f, s1o)), dot1), fc1b[p]);
  h1_mem[i1] = nm1;
  const float sp1 = nm1 > 0.5f ? 1.f : 0.f;
  h1_spk[i1] = sp1;
  sp1l[p] = sp1;
  __syncthreads();
  if (p < 4) {
    float acc = 0.f;
    for (int q = 0; q < 256; ++q) acc = __fmaf_rn(sp1l[q], fc2W[q * 4 + p], acc);
    const int i2 = s * 4 + p;
    const float m2 = h2_mem[i2], s2o = h2_spk[i2];
    const float nm2 = __fadd_rn(__fadd_rn(__fmul_rn(__fmul_rn(m2, 0.2f), __fsub_rn(1.f, s2o)), acc), fc2b[p]);
    h2_mem[i2] = nm2;
    const float sp2 = nm2 > 0.5f ? 1.f : 0.f;
    h2_spk[i2] = sp2;
    h2_sum[i2] = __fadd_rn(h2_sum[i2], sp2);
  }
}

__global__ void k_out(const float* __restrict__ h2_sum, float* __restrict__ out) {
  int i = blockIdx.x * 256 + threadIdx.x;
  if (i < SG * 4) out[i] = __fmul_rn(h2_sum[i], 0.03125f);
}

// ---------------- launch ----------------
extern "C" void kernel_launch(void* const* d_in, const int* in_sizes, int n_in,
                              void* d_out, int out_size, void* d_ws, size_t ws_size,
                              hipStream_t stream) {
  const float* x      = (const float*)d_in[0];
  const int*   ei     = (const int*)  d_in[1];
  const float* encW   = (const float*)d_in[2];
  const float* encB   = (const float*)d_in[3];
  const float* basesW = (const float*)d_in[4];
  const float* basesB = (const float*)d_in[5];
  const float* combW  = (const float*)d_in[6];
  const float* combB  = (const float*)d_in[7];
  const float* convB  = (const float*)d_in[8];
  const float* Wih    = (const float*)d_in[9];
  const float* Whh    = (const float*)d_in[10];
  const float* bih    = (const float*)d_in[11];
  const float* bhh    = (const float*)d_in[12];
  const float* fc1W   = (const float*)d_in[13];
  const float* fc1b   = (const float*)d_in[14];
  const float* fc2W   = (const float*)d_in[15];
  const float* fc2b   = (const float*)d_in[16];

  float* ws = (float*)d_ws;
  float* enc_mem = ws + OFF_ENC_MEM;
  float* enc_spk = ws + OFF_ENC_SPK;
  float* c1_mem  = ws + OFF_C1_MEM;
  float* c1_spk  = ws + OFF_C1_SPK;   // xl
  float* lhp     = ws + OFF_LH;
  float* lcp     = ws + OFF_LC;
  float* h1_mem  = ws + OFF_H1_MEM;
  float* h1_spk  = ws + OFF_H1_SPK;
  float* h2_mem  = ws + OFF_H2_MEM;
  float* h2_spk  = ws + OFF_H2_SPK;
  float* h2_sum  = ws + OFF_H2_SUM;
  float* bases   = ws + OFF_BASES;
  float* comb    = ws + OFF_COMB;
  float* gates   = ws + OFF_GATES;
  float* partp   = ws + OFF_PART;
  float* dinv    = ws + OFF_DINV;
  float* colw    = ws + OFF_COLW;
  int* ibase = (int*)((char*)d_ws + (size_t)FLOAT_END * 4);
  int* deg  = ibase + IOFF_DEG;
  int* fill = ibase + IOFF_FILL;
  int* rowp = ibase + IOFF_ROWPTR;
  int* eid  = ibase + IOFF_EID;
  int* col  = ibase + IOFF_COL;

  hipMemsetAsync(ws, 0, (size_t)ZERO_FLOATS * 4, stream);
  hipMemsetAsync(ibase, 0, 32768 * 4, stream);

  k_deg    <<<NE / 256, 256, 0, stream>>>(ei, deg);
  k_dinv   <<<NN / 256, 256, 0, stream>>>(deg, dinv);
  k_scan   <<<1, 1024, 0, stream>>>(deg, rowp);
  k_scatter<<<NE / 256, 256, 0, stream>>>(ei, rowp, fill, eid);
  k_sortadj<<<NN / 256, 256, 0, stream>>>(rowp, eid, ei, dinv, col, colw);

  for (int t = 0; t < TSTEPS; ++t) {
    k_encbases<<<NN / 64, 256, 0, stream>>>(x, encW, encB, enc_mem, enc_spk,
                                            basesW, basesB, combW, combB, bases, comb, t);
    k_aggconv <<<NN / 4, 256, 0, stream>>>(bases, comb, dinv, rowp, col, colw, convB, c1_mem, c1_spk);
    k_gpanel  <<<dim3(8, 2, NPANEL), 256, 0, stream>>>(c1_spk, lhp, Wih, Whh, partp);
    k_combine <<<2048, 256, 0, stream>>>(partp, bih, bhh, gates);
    k_cell    <<<SG, 256, 0, stream>>>(gates, lcp, lhp, fc1W, fc1b, fc2W, fc2b,
                                       h1_mem, h1_spk, h2_mem, h2_spk, h2_sum);
  }
  k_out<<<4, 256, 0, stream>>>(h2_sum, (float*)d_out);
}

// Round 7
// 7940.762 us; speedup vs baseline: 1.1338x; 1.1338x over previous
//
#include <hip/hip_runtime.h>

// ---------------- problem constants ----------------
#define NN      16384      // total nodes
#define TSTEPS  32
#define SG      256        // graphs
#define NE      262144
#define NPANEL  24         // 22 panels for xl@Wih (21x384 + 128) + 2 for lh@Whh (384+128)
#define GSTRIDE 524288u    // 256*2048 floats per panel partial

// ---------------- workspace layout (float offsets) ----------------
#define OFF_ENC_MEM   0u
#define OFF_ENC_SPK   2097152u
#define OFF_C1_MEM    4194304u
#define OFF_C1_SPK    6291456u     // == xl [256][8192]
#define OFF_LH        8388608u
#define OFF_LC        8519680u
#define OFF_H1_MEM    8650752u
#define OFF_H1_SPK    8716288u
#define OFF_H2_MEM    8781824u
#define OFF_H2_SPK    8782848u
#define OFF_H2_SUM    8783872u
#define ZERO_FLOATS   8784896u     // everything below here zeroed each launch
#define OFF_BASES     8784896u
#define OFF_COMB      9833472u
#define OFF_GATES     10357760u    // 256 x 2048
#define OFF_PART      10882048u    // 24 x 256 x 2048 panel partials
#define OFF_DINV      23464960u
#define OFF_COLW      23481344u
#define OFF_AT        23743488u    // aT [8704][256]  (xl^T rows 0..8191, lh^T rows 8192..8703)
#define FLOAT_END     25971712u
// int region (offsets from ibase)
#define IOFF_DEG      0
#define IOFF_FILL     16384
#define IOFF_ROWPTR   32768
#define IOFF_EID      49153
#define IOFF_COL      311297
#define INT_COUNT     573441

// ---------------- graph preprocessing ----------------
__global__ void k_deg(const int* __restrict__ ei, int* __restrict__ deg) {
  int e = blockIdx.x * 256 + threadIdx.x;
  if (e < NE) atomicAdd(&deg[ei[NE + e]], 1);
}

__global__ void k_dinv(const int* __restrict__ deg, float* __restrict__ dinv) {
  int n = blockIdx.x * 256 + threadIdx.x;
  if (n < NN) dinv[n] = __fdiv_rn(1.0f, __fsqrt_rn((float)(deg[n] + 1)));  // +1 self-loop
}

__global__ void k_scan(const int* __restrict__ deg, int* __restrict__ rowp) {
  __shared__ int sdata[1024];
  int tid = threadIdx.x;
  int base = tid * 16;
  int loc[16];
  int sum = 0;
  #pragma unroll
  for (int i = 0; i < 16; ++i) { loc[i] = sum; sum += deg[base + i]; }
  sdata[tid] = sum;
  __syncthreads();
  for (int off = 1; off < 1024; off <<= 1) {
    int v = 0;
    if (tid >= off) v = sdata[tid - off];
    __syncthreads();
    sdata[tid] += v;
    __syncthreads();
  }
  int excl = (tid == 0) ? 0 : sdata[tid - 1];
  #pragma unroll
  for (int i = 0; i < 16; ++i) rowp[base + i] = excl + loc[i];
  if (tid == 1023) rowp[NN] = sdata[1023];
}

__global__ void k_scatter(const int* __restrict__ ei, const int* __restrict__ rowp,
                          int* __restrict__ fill, int* __restrict__ eid) {
  int e = blockIdx.x * 256 + threadIdx.x;
  if (e >= NE) return;
  int d = ei[NE + e];
  int pos = rowp[d] + atomicAdd(&fill[d], 1);
  eid[pos] = e;
}

// sort each adjacency list by EDGE ID (unique keys) -> summation order == scatter-add order
__global__ void k_sortadj(const int* __restrict__ rowp, int* __restrict__ eid,
                          const int* __restrict__ ei, const float* __restrict__ dinv,
                          int* __restrict__ col, float* __restrict__ colw) {
  int d = blockIdx.x * 256 + threadIdx.x;
  if (d >= NN) return;
  int r0 = rowp[d], r1 = rowp[d + 1];
  for (int i = r0 + 1; i < r1; ++i) {
    int key = eid[i];
    int j = i - 1;
    while (j >= r0 && eid[j] > key) { eid[j + 1] = eid[j]; --j; }
    eid[j + 1] = key;
  }
  for (int i = r0; i < r1; ++i) {
    int s = ei[eid[i]];
    col[i] = s;
    colw[i] = dinv[s];
  }
}

// ---------------- per-timestep kernels ----------------
// fused enc LIF + bases/comb matmuls (64 nodes/block).
__global__ __launch_bounds__(256) void k_encbases(
    const float* __restrict__ x, const float* __restrict__ encW, const float* __restrict__ encB,
    float* __restrict__ enc_mem, float* __restrict__ enc_spk,
    const float* __restrict__ basesW, const float* __restrict__ basesB,
    const float* __restrict__ combW, const float* __restrict__ combB,
    float* __restrict__ bases, float* __restrict__ comb, int t) {
  __shared__ float xs[64][8];
  __shared__ float sp[64 * 129];   // [node][j]
  __shared__ float ob[64 * 65];    // bases out [node][ch]
  __shared__ float oc[64 * 33];    // comb out [node][ch]
  const int tid = threadIdx.x;
  const int nb = blockIdx.x * 64;
  #pragma unroll
  for (int r = 0; r < 2; ++r) {
    int idx = r * 256 + tid;       // 0..511
    int n = idx >> 3, c = idx & 7;
    xs[n][c] = x[(size_t)(nb + n) * 256 + (size_t)c * 32 + t];
  }
  __syncthreads();
  #pragma unroll 4
  for (int k = 0; k < 32; ++k) {
    int idx = k * 256 + tid;
    int n = idx >> 7, j = idx & 127;
    float dot = 0.f;
    #pragma unroll
    for (int c = 0; c < 8; ++c) dot = __fmaf_rn(xs[n][c], encW[c * 128 + j], dot);
    size_t gi = (size_t)nb * 128 + idx;
    float m = enc_mem[gi], s = enc_spk[gi];
    float nm = __fadd_rn(__fadd_rn(__fmul_rn(__fmul_rn(m, 0.2f), __fsub_rn(1.f, s)), dot), encB[j]);
    enc_mem[gi] = nm;
    float spike = nm > 0.5f ? 1.f : 0.f;
    enc_spk[gi] = spike;
    sp[n * 129 + j] = spike;
  }
  __syncthreads();
  const int lane = tid & 63;
  const int w = tid >> 6;
  const float* spn = sp + lane * 129;
  if (w < 2) {
    const int ch0 = w * 32;
    const float* Wp = basesW + ch0;
    float acc[32];
    #pragma unroll
    for (int c = 0; c < 32; ++c) acc[c] = 0.f;
    for (int j = 0; j < 128; ++j) {
      const float s = spn[j];
      const float* wr = Wp + j * 64;
      #pragma unroll
      for (int c = 0; c < 32; ++c) acc[c] = __fmaf_rn(s, wr[c], acc[c]);
    }
    #pragma unroll
    for (int c = 0; c < 32; ++c) ob[lane * 65 + ch0 + c] = acc[c];
  } else {
    const int ch0 = (w - 2) * 16;
    const float* Wp = combW + ch0;
    float acc[16];
    #pragma unroll
    for (int c = 0; c < 16; ++c) acc[c] = 0.f;
    for (int j = 0; j < 128; ++j) {
      const float s = spn[j];
      const float* wr = Wp + j * 32;
      #pragma unroll
      for (int c = 0; c < 16; ++c) acc[c] = __fmaf_rn(s, wr[c], acc[c]);
    }
    #pragma unroll
    for (int c = 0; c < 16; ++c) oc[lane * 33 + ch0 + c] = acc[c];
  }
  __syncthreads();
  #pragma unroll
  for (int r = 0; r < 16; ++r) {
    int idx = r * 256 + tid;
    int n = idx >> 6, ch = idx & 63;
    bases[(size_t)(nb + n) * 64 + ch] = __fadd_rn(ob[n * 65 + ch], basesB[ch]);
  }
  #pragma unroll
  for (int r = 0; r < 8; ++r) {
    int idx = r * 256 + tid;
    int n = idx >> 5, ch = idx & 31;
    comb[(size_t)(nb + n) * 32 + ch] = __fadd_rn(oc[n * 33 + ch], combB[ch]);
  }
}

// fused: symnorm aggregation (edge-order scatter-add) -> einsum -> conv LIF -> c1 spike
__global__ __launch_bounds__(256) void k_aggconv(
    const float* __restrict__ bases, const float* __restrict__ comb,
    const float* __restrict__ dinv, const int* __restrict__ rowp,
    const int* __restrict__ col, const float* __restrict__ colw,
    const float* __restrict__ convB,
    float* __restrict__ c1_mem, float* __restrict__ c1_spk) {
  __shared__ float aggl[4][64];
  __shared__ float combl[4][32];
  int w = threadIdx.x >> 6;
  int m = threadIdx.x & 63;
  int d = blockIdx.x * 4 + w;
  float dd = dinv[d];
  int r0 = rowp[d], r1 = rowp[d + 1];
  float acc = 0.f;
  for (int r = r0; r < r1; ++r) {
    int s = col[r];
    float ew  = __fmul_rn(colw[r], dd);
    float upd = __fmul_rn(ew, bases[(size_t)s * 64 + m]);
    acc = __fadd_rn(acc, upd);
  }
  {
    float ew  = __fmul_rn(dd, dd);
    float upd = __fmul_rn(ew, bases[(size_t)d * 64 + m]);
    acc = __fadd_rn(acc, upd);
  }
  aggl[w][m] = acc;
  if (m < 32) combl[w][m] = comb[(size_t)d * 32 + m];
  __syncthreads();
  #pragma unroll
  for (int half = 0; half < 2; ++half) {
    int j = m + half * 64;
    int h = j >> 4, f = j & 15;
    float cv = 0.f;
    #pragma unroll
    for (int b = 0; b < 4; ++b)
      cv = __fadd_rn(cv, __fmul_rn(combl[w][h * 4 + b], aggl[w][b * 16 + f]));
    cv = __fadd_rn(cv, convB[j]);
    int idx = d * 128 + j;
    float cm = c1_mem[idx], cs = c1_spk[idx];
    float nm = __fadd_rn(__fmul_rn(__fmul_rn(cm, 0.2f), __fsub_rn(1.f, cs)), cv);
    c1_mem[idx] = nm;
    c1_spk[idx] = nm > 0.5f ? 1.f : 0.f;
  }
}

// transpose xl [256][8192] and lh [256][512] into aT [8704][256] (LDS-tiled, coalesced both sides)
__global__ __launch_bounds__(256) void k_transpose(
    const float* __restrict__ xl, const float* __restrict__ lh, float* __restrict__ aT) {
  __shared__ float tile[64][65];
  const int b = blockIdx.x;
  const float* src; int srcld, k0, m0, kbase;
  if (b < 512) {                 // xl: 128 k-tiles x 4 m-tiles
    src = xl; srcld = 8192; k0 = (b >> 2) * 64; m0 = (b & 3) * 64; kbase = 0;
  } else {                       // lh: 8 k-tiles x 4 m-tiles
    int bb = b - 512;
    src = lh; srcld = 512; k0 = (bb >> 2) * 64; m0 = (bb & 3) * 64; kbase = 8192;
  }
  const int tr = threadIdx.x >> 6;   // 0..3
  const int tc = threadIdx.x & 63;
  #pragma unroll
  for (int it = 0; it < 16; ++it) {
    int r = it * 4 + tr;             // m-local
    tile[r][tc] = src[(size_t)(m0 + r) * srcld + k0 + tc];
  }
  __syncthreads();
  #pragma unroll
  for (int it = 0; it < 16; ++it) {
    int r = it * 4 + tr;             // k-local
    aT[(size_t)(kbase + k0 + r) * 256 + m0 + tc] = tile[tc][r];
  }
}

// one BLAS panel of the gates GEMM: part[z] = A[:, panel_z] @ B[panel_z, :]
// BM=64, BN=256: wave wv owns 16 m-rows (wave-uniform!) x 256 n; per-thread 16x4.
// A comes from aT via wave-uniform loads (-> scalar K$ path, zero LDS);
// B staged in LDS, 1 ds_read_b128 per kk per lane vs 64 fma -> VALU-bound.
// acc chain: ascending-k fma-from-0 per (m,u) within panel -> bit-exact.
__global__ __launch_bounds__(256) void k_gpanel(
    const float* __restrict__ aT,
    const float* __restrict__ Wih, const float* __restrict__ Whh,
    float* __restrict__ part) {
  __shared__ __align__(16) float Bs[16][260];   // 16.6 KB
  const int tid = threadIdx.x;
  const int ln  = tid & 63;
  const int wv  = __builtin_amdgcn_readfirstlane(tid >> 6);
  const int n0  = blockIdx.x * 256;
  const int m0  = blockIdx.y * 64;
  const int z   = blockIdx.z;

  const float* Bsrc; int kb0, kbase, klen;
  if (z < 22) { Bsrc = Wih; kb0 = z * 384; kbase = kb0;        klen = (z == 21) ? 128 : 384; }
  else        { Bsrc = Whh; kb0 = (z == 22) ? 0 : 384; kbase = 8192 + kb0; klen = (z == 22) ? 384 : 128; }

  float acc[16][4];
  #pragma unroll
  for (int i = 0; i < 16; ++i)
    #pragma unroll
    for (int j = 0; j < 4; ++j) acc[i][j] = 0.f;

  const int srow = tid >> 4;          // 0..15 (B staging row)
  const int scol = (tid & 15) * 16;   // 0..240
  const float* aTw = aT + (size_t)kbase * 256 + m0 + wv * 16;   // wave-uniform base

  const int nkt = klen >> 4;
  for (int kt = 0; kt < nkt; ++kt) {
    const int kb = kt << 4;
    __syncthreads();
    {   // stage B tile 16k x 256n (global reads 256B-contiguous per 16-thread row)
      const float* gsrc = Bsrc + (size_t)(kb0 + kb + srow) * 2048 + n0 + scol;
      const float4 v0 = ((const float4*)gsrc)[0];
      const float4 v1 = ((const float4*)gsrc)[1];
      const float4 v2 = ((const float4*)gsrc)[2];
      const float4 v3 = ((const float4*)gsrc)[3];
      float* d = &Bs[srow][scol];
      ((float4*)d)[0] = v0; ((float4*)d)[1] = v1;
      ((float4*)d)[2] = v2; ((float4*)d)[3] = v3;
    }
    __syncthreads();
    #pragma unroll
    for (int kk = 0; kk < 16; ++kk) {
      const float4* ar4 = (const float4*)(aTw + (size_t)(kb + kk) * 256);  // uniform addr
      const float4 a0 = ar4[0], a1 = ar4[1], a2 = ar4[2], a3 = ar4[3];
      const float4 bv = *(const float4*)&Bs[kk][ln * 4];
      const float am[16] = {a0.x, a0.y, a0.z, a0.w, a1.x, a1.y, a1.z, a1.w,
                            a2.x, a2.y, a2.z, a2.w, a3.x, a3.y, a3.z, a3.w};
      #pragma unroll
      for (int i = 0; i < 16; ++i) {
        acc[i][0] = __fmaf_rn(am[i], bv.x, acc[i][0]);
        acc[i][1] = __fmaf_rn(am[i], bv.y, acc[i][1]);
        acc[i][2] = __fmaf_rn(am[i], bv.z, acc[i][2]);
        acc[i][3] = __fmaf_rn(am[i], bv.w, acc[i][3]);
      }
    }
  }
  float* dst = part + (size_t)z * GSTRIDE + (size_t)(m0 + wv * 16) * 2048 + n0 + ln * 4;
  #pragma unroll
  for (int i = 0; i < 16; ++i)
    *(float4*)(dst + (size_t)i * 2048) =
        make_float4(acc[i][0], acc[i][1], acc[i][2], acc[i][3]);
}

// combine panel partials strictly left-to-right (matches round-2 "tih += accP" chain)
__global__ __launch_bounds__(256) void k_combine(
    const float* __restrict__ part, const float* __restrict__ bih,
    const float* __restrict__ bhh, float* __restrict__ gates) {
  const int idx = blockIdx.x * 256 + threadIdx.x;    // m*2048 + u
  const float* p = part + idx;
  float tih = p[0];
  #pragma unroll
  for (int zz = 1; zz < 22; ++zz) tih = __fadd_rn(tih, p[(size_t)zz * GSTRIDE]);
  const float thh = __fadd_rn(p[22u * GSTRIDE], p[23u * GSTRIDE]);
  const int u = idx & 2047;
  gates[idx] = __fadd_rn(__fadd_rn(__fadd_rn(tih, bih[u]), thh), bhh[u]);
}

// fused: gate spikes -> LSTM cell -> fc1 LIF (384+128 panels) -> fc2 LIF -> h2 accum
__global__ __launch_bounds__(256) void k_cell(
    const float* __restrict__ gates,
    float* __restrict__ lc, float* __restrict__ lh,
    const float* __restrict__ fc1W, const float* __restrict__ fc1b,
    const float* __restrict__ fc2W, const float* __restrict__ fc2b,
    float* __restrict__ h1_mem, float* __restrict__ h1_spk,
    float* __restrict__ h2_mem, float* __restrict__ h2_spk, float* __restrict__ h2_sum) {
  __shared__ float lhl[512];
  __shared__ float sp1l[256];
  const int s = blockIdx.x;
  const int p = threadIdx.x;
  #pragma unroll
  for (int half = 0; half < 2; ++half) {
    const int h = p + half * 256;
    const float giv = gates[(size_t)s * 2048 + h];
    const float gfv = gates[(size_t)s * 2048 + 512 + h];
    const float ggv = gates[(size_t)s * 2048 + 1024 + h];
    const float gov = gates[(size_t)s * 2048 + 1536 + h];
    const float iv = giv > 0.f ? 1.f : 0.f;
    const float fv = gfv > 0.f ? 1.f : 0.f;
    const float gv = ggv > 0.f ? 1.f : 0.f;
    const float ov = gov > 0.f ? 1.f : 0.f;
    const int li = s * 512 + h;
    const float lcv = __fadd_rn(__fmul_rn(fv, lc[li]), __fmul_rn(iv, gv));
    lc[li] = lcv;
    const float lhv = __fmul_rn(lcv, ov);
    lh[li] = lhv;
    lhl[h] = lhv;
  }
  __syncthreads();
  float a0 = 0.f, a1 = 0.f;
  #pragma unroll 8
  for (int q = 0; q < 384; ++q) a0 = __fmaf_rn(lhl[q], fc1W[q * 256 + p], a0);
  #pragma unroll 8
  for (int q = 384; q < 512; ++q) a1 = __fmaf_rn(lhl[q], fc1W[q * 256 + p], a1);
  const float dot1 = __fadd_rn(a0, a1);
  const int i1 = s * 256 + p;
  const float m1 = h1_mem[i1], s1o = h1_spk[i1];
  const float nm1 = __fadd_rn(__fadd_rn(__fmul_rn(__fmul_rn(m1, 0.2f), __fsub_rn(1.f, s1o)), dot1), fc1b[p]);
  h1_mem[i1] = nm1;
  const float sp1 = nm1 > 0.5f ? 1.f : 0.f;
  h1_spk[i1] = sp1;
  sp1l[p] = sp1;
  __syncthreads();
  if (p < 4) {
    float acc = 0.f;
    for (int q = 0; q < 256; ++q) acc = __fmaf_rn(sp1l[q], fc2W[q * 4 + p], acc);
    const int i2 = s * 4 + p;
    const float m2 = h2_mem[i2], s2o = h2_spk[i2];
    const float nm2 = __fadd_rn(__fadd_rn(__fmul_rn(__fmul_rn(m2, 0.2f), __fsub_rn(1.f, s2o)), acc), fc2b[p]);
    h2_mem[i2] = nm2;
    const float sp2 = nm2 > 0.5f ? 1.f : 0.f;
    h2_spk[i2] = sp2;
    h2_sum[i2] = __fadd_rn(h2_sum[i2], sp2);
  }
}

__global__ void k_out(const float* __restrict__ h2_sum, float* __restrict__ out) {
  int i = blockIdx.x * 256 + threadIdx.x;
  if (i < SG * 4) out[i] = __fmul_rn(h2_sum[i], 0.03125f);
}

// ---------------- launch ----------------
extern "C" void kernel_launch(void* const* d_in, const int* in_sizes, int n_in,
                              void* d_out, int out_size, void* d_ws, size_t ws_size,
                              hipStream_t stream) {
  const float* x      = (const float*)d_in[0];
  const int*   ei     = (const int*)  d_in[1];
  const float* encW   = (const float*)d_in[2];
  const float* encB   = (const float*)d_in[3];
  const float* basesW = (const float*)d_in[4];
  const float* basesB = (const float*)d_in[5];
  const float* combW  = (const float*)d_in[6];
  const float* combB  = (const float*)d_in[7];
  const float* convB  = (const float*)d_in[8];
  const float* Wih    = (const float*)d_in[9];
  const float* Whh    = (const float*)d_in[10];
  const float* bih    = (const float*)d_in[11];
  const float* bhh    = (const float*)d_in[12];
  const float* fc1W   = (const float*)d_in[13];
  const float* fc1b   = (const float*)d_in[14];
  const float* fc2W   = (const float*)d_in[15];
  const float* fc2b   = (const float*)d_in[16];

  float* ws = (float*)d_ws;
  float* enc_mem = ws + OFF_ENC_MEM;
  float* enc_spk = ws + OFF_ENC_SPK;
  float* c1_mem  = ws + OFF_C1_MEM;
  float* c1_spk  = ws + OFF_C1_SPK;   // xl
  float* lhp     = ws + OFF_LH;
  float* lcp     = ws + OFF_LC;
  float* h1_mem  = ws + OFF_H1_MEM;
  float* h1_spk  = ws + OFF_H1_SPK;
  float* h2_mem  = ws + OFF_H2_MEM;
  float* h2_spk  = ws + OFF_H2_SPK;
  float* h2_sum  = ws + OFF_H2_SUM;
  float* bases   = ws + OFF_BASES;
  float* comb    = ws + OFF_COMB;
  float* gates   = ws + OFF_GATES;
  float* partp   = ws + OFF_PART;
  float* dinv    = ws + OFF_DINV;
  float* colw    = ws + OFF_COLW;
  float* aT      = ws + OFF_AT;
  int* ibase = (int*)((char*)d_ws + (size_t)FLOAT_END * 4);
  int* deg  = ibase + IOFF_DEG;
  int* fill = ibase + IOFF_FILL;
  int* rowp = ibase + IOFF_ROWPTR;
  int* eid  = ibase + IOFF_EID;
  int* col  = ibase + IOFF_COL;

  hipMemsetAsync(ws, 0, (size_t)ZERO_FLOATS * 4, stream);
  hipMemsetAsync(ibase, 0, 32768 * 4, stream);

  k_deg    <<<NE / 256, 256, 0, stream>>>(ei, deg);
  k_dinv   <<<NN / 256, 256, 0, stream>>>(deg, dinv);
  k_scan   <<<1, 1024, 0, stream>>>(deg, rowp);
  k_scatter<<<NE / 256, 256, 0, stream>>>(ei, rowp, fill, eid);
  k_sortadj<<<NN / 256, 256, 0, stream>>>(rowp, eid, ei, dinv, col, colw);

  for (int t = 0; t < TSTEPS; ++t) {
    k_encbases <<<NN / 64, 256, 0, stream>>>(x, encW, encB, enc_mem, enc_spk,
                                             basesW, basesB, combW, combB, bases, comb, t);
    k_aggconv  <<<NN / 4, 256, 0, stream>>>(bases, comb, dinv, rowp, col, colw, convB, c1_mem, c1_spk);
    k_transpose<<<544, 256, 0, stream>>>(c1_spk, lhp, aT);
    k_gpanel   <<<dim3(8, 4, NPANEL), 256, 0, stream>>>(aT, Wih, Whh, partp);
    k_combine  <<<2048, 256, 0, stream>>>(partp, bih, bhh, gates);
    k_cell     <<<SG, 256, 0, stream>>>(gates, lcp, lhp, fc1W, fc1b, fc2W, fc2b,
                                        h1_mem, h1_spk, h2_mem, h2_spk, h2_sum);
  }
  k_out<<<4, 256, 0, stream>>>(h2_sum, (float*)d_out);
}